// Round 24
// baseline (63.020 us; speedup 1.0000x reference)
//
#include <hip/hip_runtime.h>
#include <hip/hip_bf16.h>

// Problem constants
#define XH   64
#define XW   64
#define CIN  256
#define COUT 256
#define BATCH 4
#define KK9  9
#define M_TOT 16384      // BATCH*XH*XW
#define K_TOT 2304       // KK9*CIN
#define NKSTEP 36        // K_TOT/64

typedef __attribute__((ext_vector_type(8))) short short8;
typedef __attribute__((ext_vector_type(4))) float f32x4;

// Workspace layout (bytes)
#define XT_OFF   0
#define XT_BYTES (BATCH*4096*CIN*2)           // 8,388,608 (bf16)
#define WT_OFF   (XT_OFF + XT_BYTES)
#define WT_BYTES (COUT*K_TOT*2)               // 1,179,648  Wt3: A-fragment-ordered
#define WOT_OFF  (WT_OFF + WT_BYTES)
#define WOT_BYTES (36*2*2*64*8*2)             // 147,456    Wot3: A-fragment-ordered

__device__ __forceinline__ float b2f(short s) {
  union { float f; unsigned u; } x;
  x.u = ((unsigned)(unsigned short)s) << 16;
  return x.f;
}

struct Taps { short8 t00, t01, t10, t11; };

// ---------------------------------------------------------------------------
// K_PREP: merged k0 + k0b + kt (unchanged from R21/R23).
// ---------------------------------------------------------------------------
__global__ __launch_bounds__(256) void k_prep(const float* __restrict__ x,
                                              const float* __restrict__ woff,
                                              const float* __restrict__ wconv,
                                              __hip_bfloat16* __restrict__ Wt3,
                                              __hip_bfloat16* __restrict__ Wot3,
                                              __hip_bfloat16* __restrict__ xTh) {
  int blk = blockIdx.x;
  if (blk < 2304) {
    int e = blk * 256 + threadIdx.x;
    int j3   = e & 7;
    int lane = (e >> 3) & 63;
    int kc   = (e >> 9) & 1;
    int og   = (e >> 10) & 15;
    int tk   = e >> 14;
    int o = og * 16 + (lane & 15);
    int k = tk * 64 + kc * 32 + ((lane >> 4) << 3) + j3;
    int kk = k >> 8, c = k & 255;
    float v = wconv[(o * CIN + c) * KK9 + kk];
    Wt3[e] = __float2bfloat16(v);
  } else if (blk < 2592) {
    int e = (blk - 2304) * 256 + threadIdx.x;
    int j3   = e & 7;
    int lane = (e >> 3) & 63;
    int kc   = (e >> 9) & 1;
    int wc   = (e >> 10) & 1;
    int tk   = e >> 11;
    int oc = wc * 16 + (lane & 15);
    int k = tk * 64 + kc * 32 + ((lane >> 4) << 3) + j3;
    int kk = k >> 8, c = k & 255;
    float v = (oc < 27) ? woff[((size_t)(oc * 256 + c)) * 9 + kk] : 0.f;
    Wot3[e] = __float2bfloat16(v);
  } else {
    __shared__ float t[64][65];
    int tb = blk - 2592;
    int hwg = tb & 63;
    int cg  = (tb >> 6) & 3;
    int b   = tb >> 8;
    int hw0 = hwg * 64, c0 = cg * 64;
    int l = threadIdx.x & 63, q = threadIdx.x >> 6;
    const float* xb = x + ((size_t)(b * 256 + c0) << 12) + hw0;
#pragma unroll
    for (int i = 0; i < 16; ++i) {
      int cl = q * 16 + i;
      t[cl][l] = xb[((size_t)cl << 12) + l];
    }
    __syncthreads();
    __hip_bfloat16* xTb = xTh + (((size_t)b << 12) + hw0) * 256 + c0;
#pragma unroll
    for (int i = 0; i < 16; ++i) {
      int hwl = q * 16 + i;
      xTb[(size_t)hwl * 256 + l] = __float2bfloat16(t[l][hwl]);
    }
  }
}

// ---------------------------------------------------------------------------
// K23: fused. 32 m x 256 o per block, grid 512 (2 blocks/CU), 256 thr.
// Phase-1: kk-staged offset-conv GEMM (unchanged, compiler-managed).
// Phase-2: manual-vmcnt asm pipeline. All loop VMEM is inline-asm (12
// loads/step: W(tk+1)[8] + taps(tk+2)[4]); counted waits vmcnt(12)/vmcnt(4);
// sched_barrier(0) after issue group and after each wait (rule #18 both
// directions); clean vmcnt(0) baseline entering phase-2 and before epilogue.
// VGPR budget: ~170 named regs under the 256 cap of launch_bounds(256,2)
// (R18's crash was demanding 130+ under a 128 cap -> spills broke counting).
// ---------------------------------------------------------------------------
__global__ __launch_bounds__(256, 2) void k23_fused(const __hip_bfloat16* __restrict__ xTh,
                                                    const __hip_bfloat16* __restrict__ Wt3,
                                                    const __hip_bfloat16* __restrict__ Wot3,
                                                    const float* __restrict__ boff,
                                                    float* __restrict__ out) {
  __shared__ __align__(16) __hip_bfloat16 sPatch[4][32 * 64];  // 16 KB
  __shared__ float sOM[32][33];
  __shared__ float sw00[288], sw01[288], sw10[288], sw11[288];
  __shared__ int   so00[288], so01[288], so10[288], so11[288];

  __hip_bfloat16 (*sPV)[32 * 64] = sPatch;

  int bid = blockIdx.x;
  int tm = ((bid & 7) << 6) | (bid >> 3);   // chunked XCD swizzle, 0..511
  int tid = threadIdx.x;
  int wv = tid >> 6, lane = tid & 63;
  int lo = lane & 15, hi = lane >> 4;
  int b = tm >> 7;
  int m0 = tm * 32;

  // ===================== PHASE 1 (unchanged) =====================
  {
    int wr = wv >> 1, wc = wv & 1;
    int prow = tid >> 3;
    int pkb  = (tid & 7) * 8;
    int pcolz = pkb ^ ((prow & 7) << 3);
    int m_s = m0 + prow;
    int hw_s = m_s & 4095, h_s = hw_s >> 6, w_s = hw_s & 63;

    f32x4 acc1 = {0.f, 0.f, 0.f, 0.f};
    const short8 zero8 = {0,0,0,0,0,0,0,0};

    for (int kk = 0; kk < KK9; ++kk) {
      int ky = kk / 3, kx = kk - ky * 3;
      int yy = h_s + ky - 1, xx = w_s + kx - 1;
      bool valid = ((unsigned)yy < 64u) && ((unsigned)xx < 64u);
      int cy = min(max(yy, 0), 63), cx = min(max(xx, 0), 63);
      const __hip_bfloat16* src = xTh + ((((size_t)b << 12) + cy * 64 + cx) << 8) + pkb;
#pragma unroll
      for (int cc = 0; cc < 4; ++cc) {
        short8 h8 = valid ? *(const short8*)(src + cc * 64) : zero8;
        *(short8*)&sPatch[cc][prow * 64 + pcolz] = h8;
      }
      __syncthreads();
#pragma unroll
      for (int cc = 0; cc < 4; ++cc) {
        int tk = kk * 4 + cc;
#pragma unroll
        for (int kc = 0; kc < 2; ++kc) {
          int cz = (kc * 32 + hi * 8) ^ ((lo & 7) << 3);
          short8 bfr = *(const short8*)&sPatch[cc][(wr * 16 + lo) * 64 + cz];
          short8 a = *(const short8*)((const char*)Wot3
                      + ((((size_t)tk * 2 + wc) * 2 + kc) << 10) + lane * 16);
          acc1 = __builtin_amdgcn_mfma_f32_16x16x32_bf16(a, bfr, acc1, 0, 0, 0);
        }
      }
      __syncthreads();
    }

    int oc0 = wc * 16 + hi * 4;
#pragma unroll
    for (int r = 0; r < 4; ++r) {
      float bias = (oc0 + r < 27) ? boff[oc0 + r] : 0.f;
      sOM[wr * 16 + lo][oc0 + r] = acc1[r] + bias;
    }
  }
  __syncthreads();

  // ============== PHASE 2 prologue A: gather params from sOM ==============
  for (int it = tid; it < 288; it += 256) {
    int kk = it >> 5, row = it & 31;
    int m = m0 + row;
    int hw = m & 4095, h = hw >> 6, w = hw & 63;
    float dy = sOM[row][2 * kk];
    float dx = sOM[row][2 * kk + 1];
    float mz = sOM[row][18 + kk];
    int ky = kk / 3, kx = kk - ky * 3;
    float py = dy + (float)(h - 1 + ky);
    float px = dx + (float)(w - 1 + kx);
    float y0f = floorf(py), x0f = floorf(px);
    float wy = py - y0f, wx = px - x0f;
    int y0 = (int)y0f, x0 = (int)x0f;
    bool vy0 = (unsigned)y0 < 64u, vy1 = (unsigned)(y0 + 1) < 64u;
    bool vx0 = (unsigned)x0 < 64u, vx1 = (unsigned)(x0 + 1) < 64u;
    int cy0 = min(max(y0, 0), 63), cy1 = min(max(y0 + 1, 0), 63);
    int cx0 = min(max(x0, 0), 63), cx1 = min(max(x0 + 1, 0), 63);
    float mask = 1.f / (1.f + __expf(-mz));
    sw00[it] = (vy0 && vx0) ? (1.f - wy) * (1.f - wx) * mask : 0.f;
    sw01[it] = (vy0 && vx1) ? (1.f - wy) * wx * mask : 0.f;
    sw10[it] = (vy1 && vx0) ? wy * (1.f - wx) * mask : 0.f;
    sw11[it] = (vy1 && vx1) ? wy * wx * mask : 0.f;
    so00[it] = cy0 * 64 + cx0;
    so01[it] = cy0 * 64 + cx1;
    so10[it] = cy1 * 64 + cx0;
    so11[it] = cy1 * 64 + cx1;
  }
  __syncthreads();

  // ===================== PHASE 2: main GEMM (manual vmcnt) =================
  const __hip_bfloat16* xb = xTh + ((size_t)b << 20);
  int vrow = tid >> 3;
  int chq  = tid & 7;
  int colz = (chq * 8) ^ ((vrow & 7) << 3);

  // clean vmcnt baseline: drain all compiler-issued loads (phase-1 etc.)
  asm volatile("s_waitcnt vmcnt(0)" ::: "memory");
  __builtin_amdgcn_sched_barrier(0);

  auto issueW = [&](int tkq, short8 (&aw)[8]) {
#pragma unroll
    for (int fo = 0; fo < 4; ++fo)
#pragma unroll
      for (int kc = 0; kc < 2; ++kc) {
        const void* p = (const char*)Wt3
            + ((((size_t)tkq * 16 + (wv * 4 + fo)) * 2 + kc) << 10) + lane * 16;
        asm volatile("global_load_dwordx4 %0, %1, off" : "=v"(aw[fo * 2 + kc]) : "v"(p));
      }
  };
  auto issueTaps = [&](int tkq, Taps& T) {
    int it = (tkq >> 2) * 32 + vrow;
    const __hip_bfloat16* base = xb + (tkq & 3) * 64 + chq * 8;
    const void* p0 = base + (size_t)so00[it] * 256;
    const void* p1 = base + (size_t)so01[it] * 256;
    const void* p2 = base + (size_t)so10[it] * 256;
    const void* p3 = base + (size_t)so11[it] * 256;
    asm volatile("global_load_dwordx4 %0, %1, off" : "=v"(T.t00) : "v"(p0));
    asm volatile("global_load_dwordx4 %0, %1, off" : "=v"(T.t01) : "v"(p1));
    asm volatile("global_load_dwordx4 %0, %1, off" : "=v"(T.t10) : "v"(p2));
    asm volatile("global_load_dwordx4 %0, %1, off" : "=v"(T.t11) : "v"(p3));
  };
  auto buildV = [&](int tkq, const Taps& T, int buf) {
    int it = (tkq >> 2) * 32 + vrow;
    float a00 = sw00[it], a01 = sw01[it], a10 = sw10[it], a11 = sw11[it];
    __hip_bfloat16 h8[8];
#pragma unroll
    for (int j = 0; j < 8; ++j) {
      float v = a00 * b2f(T.t00[j]) + a01 * b2f(T.t01[j])
              + a10 * b2f(T.t10[j]) + a11 * b2f(T.t11[j]);
      h8[j] = __float2bfloat16(v);
    }
    *(short8*)&sPV[buf][vrow * 64 + colz] = *(const short8*)h8;
  };

  f32x4 zero4 = {0.f, 0.f, 0.f, 0.f};
  f32x4 acc[4][2];
#pragma unroll
  for (int fo = 0; fo < 4; ++fo)
#pragma unroll
    for (int fm = 0; fm < 2; ++fm) acc[fo][fm] = zero4;

  Taps TA, TB;
  short8 awA[8], awB[8];
  // prologue: W(0)[8] + taps(0)[4] + taps(1)[4] = 16 outstanding
  issueW(0, awA);
  issueTaps(0, TA);
  issueTaps(1, TB);
  __builtin_amdgcn_sched_barrier(0);
  asm volatile("s_waitcnt vmcnt(4)" ::: "memory");   // drains W(0)+taps(0); taps(1) in flight
  __builtin_amdgcn_sched_barrier(0);
  buildV(0, TA, 0);
  asm volatile("s_waitcnt lgkmcnt(0)" ::: "memory");
  __builtin_amdgcn_s_barrier();

  auto body = [&](int tk, Taps& Tuse, Taps& Tload,
                  short8 (&awUse)[8], short8 (&awLoad)[8]) {
    int cb = tk & 1, nb = cb ^ 1;
    int tk1 = min(tk + 1, NKSTEP - 1), tk2 = min(tk + 2, NKSTEP - 1);
    // issue group: 12 loads (W(tk+1)[8], taps(tk+2)[4])
    issueW(tk1, awLoad);
    issueTaps(tk2, Tload);
    __builtin_amdgcn_sched_barrier(0);
    // enter with taps(tk+1)[4] outstanding -> 16 total; drain the oldest 4
    asm volatile("s_waitcnt vmcnt(12)" ::: "memory");
    __builtin_amdgcn_sched_barrier(0);
    buildV(tk1, Tuse, nb);            // taps(tk+1) now valid

    __builtin_amdgcn_s_setprio(1);
#pragma unroll
    for (int kc = 0; kc < 2; ++kc) {
      int cz = (kc * 32 + hi * 8) ^ ((lo & 7) << 3);
      short8 bv[2];
#pragma unroll
      for (int fm = 0; fm < 2; ++fm)
        bv[fm] = *(const short8*)&sPV[cb][(fm * 16 + lo) * 64 + cz];
#pragma unroll
      for (int fo = 0; fo < 4; ++fo)
#pragma unroll
        for (int fm = 0; fm < 2; ++fm)
          acc[fo][fm] = __builtin_amdgcn_mfma_f32_16x16x32_bf16(awUse[fo * 2 + kc], bv[fm], acc[fo][fm], 0, 0, 0);
    }
    __builtin_amdgcn_s_setprio(0);

    asm volatile("s_waitcnt lgkmcnt(0)" ::: "memory");  // V(tk+1) ds_writes done
    if (tk + 1 < NKSTEP) __builtin_amdgcn_s_barrier();
    // drain W(tk+1) (leaves taps(tk+2)[4] in flight) -> awLoad valid next iter
    asm volatile("s_waitcnt vmcnt(4)" ::: "memory");
    __builtin_amdgcn_sched_barrier(0);
  };

  for (int tkp = 0; tkp < NKSTEP; tkp += 2) {
    body(tkp,     TB, TA, awA, awB);
    body(tkp + 1, TA, TB, awB, awA);
  }

  // drain all asm loads before compiler-managed epilogue stores
  asm volatile("s_waitcnt vmcnt(0)" ::: "memory");
  __builtin_amdgcn_sched_barrier(0);

  // epilogue
  int hwbase = m0 & 4095;
#pragma unroll
  for (int fo = 0; fo < 4; ++fo) {
    int o = wv * 64 + fo * 16 + hi * 4;
#pragma unroll
    for (int fm = 0; fm < 2; ++fm) {
      int mloc = hwbase + fm * 16 + lo;
#pragma unroll
      for (int r = 0; r < 4; ++r)
        out[((size_t)(b * 256 + o + r)) * 4096 + mloc] = acc[fo][fm][r];
    }
  }
}

// ---------------------------------------------------------------------------
extern "C" void kernel_launch(void* const* d_in, const int* in_sizes, int n_in,
                              void* d_out, int out_size, void* d_ws, size_t ws_size,
                              hipStream_t stream) {
  (void)in_sizes; (void)n_in; (void)out_size; (void)ws_size;
  const float* x     = (const float*)d_in[0];
  const float* woff  = (const float*)d_in[1];
  const float* boff  = (const float*)d_in[2];
  const float* wconv = (const float*)d_in[3];
  char* ws = (char*)d_ws;
  __hip_bfloat16* xTh  = (__hip_bfloat16*)(ws + XT_OFF);
  __hip_bfloat16* Wt3  = (__hip_bfloat16*)(ws + WT_OFF);
  __hip_bfloat16* Wot3 = (__hip_bfloat16*)(ws + WOT_OFF);
  float* out = (float*)d_out;

  hipLaunchKernelGGL(k_prep,    dim3(3616), dim3(256), 0, stream, x, woff, wconv, Wt3, Wot3, xTh);
  hipLaunchKernelGGL(k23_fused, dim3(512),  dim3(256), 0, stream, xTh, Wt3, Wot3, boff, out);
}

// Round 25
// 61.743 us; speedup vs baseline: 1.0207x; 1.0207x over previous
//
#include <hip/hip_runtime.h>
#include <hip/hip_bf16.h>

// Problem constants
#define XH   64
#define XW   64
#define CIN  256
#define COUT 256
#define BATCH 4
#define KK9  9
#define M_TOT 16384      // BATCH*XH*XW
#define K_TOT 2304       // KK9*CIN
#define NKSTEP 36        // K_TOT/64

typedef __attribute__((ext_vector_type(8))) short short8;
typedef __attribute__((ext_vector_type(4))) float f32x4;

// Workspace layout (bytes)
#define XT_OFF   0
#define XT_BYTES (BATCH*4096*CIN*2)           // 8,388,608 (bf16)
#define WT_OFF   (XT_OFF + XT_BYTES)
#define WT_BYTES (COUT*K_TOT*2)               // 1,179,648  Wt3: A-fragment-ordered
#define WOT_OFF  (WT_OFF + WT_BYTES)
#define WOT_BYTES (36*2*2*64*8*2)             // 147,456    Wot3: A-fragment-ordered

__device__ __forceinline__ float b2f(short s) {
  union { float f; unsigned u; } x;
  x.u = ((unsigned)(unsigned short)s) << 16;
  return x.f;
}

struct Taps { short8 t00, t01, t10, t11; };

// ---------------------------------------------------------------------------
// K_PREP: merged k0 + k0b + kt (mutually independent; one dispatch removes
// two kernel-boundary gaps and runs them concurrently).
// blocks [0,2304)      : Wt3  (w_conv -> A-fragment order)
// blocks [2304,2592)   : Wot3 (w_off  -> A-fragment order, oc>=27 padded)
// blocks [2592,3616)   : xTh  (transpose x -> [b][hw][c] bf16)
// ---------------------------------------------------------------------------
__global__ __launch_bounds__(256) void k_prep(const float* __restrict__ x,
                                              const float* __restrict__ woff,
                                              const float* __restrict__ wconv,
                                              __hip_bfloat16* __restrict__ Wt3,
                                              __hip_bfloat16* __restrict__ Wot3,
                                              __hip_bfloat16* __restrict__ xTh) {
  int blk = blockIdx.x;
  if (blk < 2304) {
    // ---- k0: Wt3[tk(36)][og(16)][kc(2)][lane(64)][j(8)] ----
    int e = blk * 256 + threadIdx.x;           // < 589824
    int j3   = e & 7;
    int lane = (e >> 3) & 63;
    int kc   = (e >> 9) & 1;
    int og   = (e >> 10) & 15;
    int tk   = e >> 14;
    int o = og * 16 + (lane & 15);
    int k = tk * 64 + kc * 32 + ((lane >> 4) << 3) + j3;
    int kk = k >> 8, c = k & 255;
    float v = wconv[(o * CIN + c) * KK9 + kk];
    Wt3[e] = __float2bfloat16(v);
  } else if (blk < 2592) {
    // ---- k0b: Wot3[tk(36)][wc(2)][kc(2)][lane(64)][j(8)] ----
    int e = (blk - 2304) * 256 + threadIdx.x;  // < 73728
    int j3   = e & 7;
    int lane = (e >> 3) & 63;
    int kc   = (e >> 9) & 1;
    int wc   = (e >> 10) & 1;
    int tk   = e >> 11;
    int oc = wc * 16 + (lane & 15);
    int k = tk * 64 + kc * 32 + ((lane >> 4) << 3) + j3;
    int kk = k >> 8, c = k & 255;
    float v = (oc < 27) ? woff[((size_t)(oc * 256 + c)) * 9 + kk] : 0.f;
    Wot3[e] = __float2bfloat16(v);
  } else {
    // ---- kt: transpose 64hw x 64c tile via LDS ----
    __shared__ float t[64][65];
    int tb = blk - 2592;                       // 0..1023
    int hwg = tb & 63;
    int cg  = (tb >> 6) & 3;
    int b   = tb >> 8;
    int hw0 = hwg * 64, c0 = cg * 64;
    int l = threadIdx.x & 63, q = threadIdx.x >> 6;
    const float* xb = x + ((size_t)(b * 256 + c0) << 12) + hw0;
#pragma unroll
    for (int i = 0; i < 16; ++i) {
      int cl = q * 16 + i;
      t[cl][l] = xb[((size_t)cl << 12) + l];
    }
    __syncthreads();
    __hip_bfloat16* xTb = xTh + (((size_t)b << 12) + hw0) * 256 + c0;
#pragma unroll
    for (int i = 0; i < 16; ++i) {
      int hwl = q * 16 + i;
      xTb[(size_t)hwl * 256 + l] = __float2bfloat16(t[l][hwl]);
    }
  }
}

// ---------------------------------------------------------------------------
// K23: FULLY fused (best measured body). 32 m x 256 o per block, grid 512
// (2 blocks/CU), 256 thr (4 waves).
// Phase-1 kk-staged offset-conv GEMM -> sOM; phase-2 deformable gather +
// main GEMM (W-frags direct from L2; taps reg-staged; sV dbuf; 1 barrier/step).
// ---------------------------------------------------------------------------
__global__ __launch_bounds__(256, 2) void k23_fused(const __hip_bfloat16* __restrict__ xTh,
                                                    const __hip_bfloat16* __restrict__ Wt3,
                                                    const __hip_bfloat16* __restrict__ Wot3,
                                                    const float* __restrict__ boff,
                                                    float* __restrict__ out) {
  __shared__ __align__(16) __hip_bfloat16 sPatch[4][32 * 64];  // 16 KB (ph1: 4 cc sub-tiles; ph2: sPV dbuf)
  __shared__ float sOM[32][33];                                 // padded
  __shared__ float sw00[288], sw01[288], sw10[288], sw11[288];
  __shared__ int   so00[288], so01[288], so10[288], so11[288];

  __hip_bfloat16 (*sPV)[32 * 64] = sPatch;

  int bid = blockIdx.x;
  int tm = ((bid & 7) << 6) | (bid >> 3);   // chunked XCD swizzle, 0..511
  int tid = threadIdx.x;
  int wv = tid >> 6, lane = tid & 63;
  int lo = lane & 15, hi = lane >> 4;
  int b = tm >> 7;
  int m0 = tm * 32;

  // ===================== PHASE 1: om for own 32 rows (kk-staged) ==========
  {
    int wr = wv >> 1, wc = wv & 1;
    int prow = tid >> 3;
    int pkb  = (tid & 7) * 8;
    int pcolz = pkb ^ ((prow & 7) << 3);
    int m_s = m0 + prow;
    int hw_s = m_s & 4095, h_s = hw_s >> 6, w_s = hw_s & 63;

    f32x4 acc1 = {0.f, 0.f, 0.f, 0.f};
    const short8 zero8 = {0,0,0,0,0,0,0,0};

    for (int kk = 0; kk < KK9; ++kk) {
      int ky = kk / 3, kx = kk - ky * 3;
      int yy = h_s + ky - 1, xx = w_s + kx - 1;
      bool valid = ((unsigned)yy < 64u) && ((unsigned)xx < 64u);
      int cy = min(max(yy, 0), 63), cx = min(max(xx, 0), 63);
      const __hip_bfloat16* src = xTh + ((((size_t)b << 12) + cy * 64 + cx) << 8) + pkb;
#pragma unroll
      for (int cc = 0; cc < 4; ++cc) {
        short8 h8 = valid ? *(const short8*)(src + cc * 64) : zero8;
        *(short8*)&sPatch[cc][prow * 64 + pcolz] = h8;
      }
      __syncthreads();
#pragma unroll
      for (int cc = 0; cc < 4; ++cc) {
        int tk = kk * 4 + cc;
#pragma unroll
        for (int kc = 0; kc < 2; ++kc) {
          int cz = (kc * 32 + hi * 8) ^ ((lo & 7) << 3);
          short8 bfr = *(const short8*)&sPatch[cc][(wr * 16 + lo) * 64 + cz];
          short8 a = *(const short8*)((const char*)Wot3
                      + ((((size_t)tk * 2 + wc) * 2 + kc) << 10) + lane * 16);
          acc1 = __builtin_amdgcn_mfma_f32_16x16x32_bf16(a, bfr, acc1, 0, 0, 0);
        }
      }
      __syncthreads();
    }

    int oc0 = wc * 16 + hi * 4;
#pragma unroll
    for (int r = 0; r < 4; ++r) {
      float bias = (oc0 + r < 27) ? boff[oc0 + r] : 0.f;
      sOM[wr * 16 + lo][oc0 + r] = acc1[r] + bias;
    }
  }
  __syncthreads();

  // ============== PHASE 2 prologue A: gather params from sOM ==============
  for (int it = tid; it < 288; it += 256) {
    int kk = it >> 5, row = it & 31;
    int m = m0 + row;
    int hw = m & 4095, h = hw >> 6, w = hw & 63;
    float dy = sOM[row][2 * kk];
    float dx = sOM[row][2 * kk + 1];
    float mz = sOM[row][18 + kk];
    int ky = kk / 3, kx = kk - ky * 3;
    float py = dy + (float)(h - 1 + ky);
    float px = dx + (float)(w - 1 + kx);
    float y0f = floorf(py), x0f = floorf(px);
    float wy = py - y0f, wx = px - x0f;
    int y0 = (int)y0f, x0 = (int)x0f;
    bool vy0 = (unsigned)y0 < 64u, vy1 = (unsigned)(y0 + 1) < 64u;
    bool vx0 = (unsigned)x0 < 64u, vx1 = (unsigned)(x0 + 1) < 64u;
    int cy0 = min(max(y0, 0), 63), cy1 = min(max(y0 + 1, 0), 63);
    int cx0 = min(max(x0, 0), 63), cx1 = min(max(x0 + 1, 0), 63);
    float mask = 1.f / (1.f + __expf(-mz));
    sw00[it] = (vy0 && vx0) ? (1.f - wy) * (1.f - wx) * mask : 0.f;
    sw01[it] = (vy0 && vx1) ? (1.f - wy) * wx * mask : 0.f;
    sw10[it] = (vy1 && vx0) ? wy * (1.f - wx) * mask : 0.f;
    sw11[it] = (vy1 && vx1) ? wy * wx * mask : 0.f;
    so00[it] = cy0 * 64 + cx0;
    so01[it] = cy0 * 64 + cx1;
    so10[it] = cy1 * 64 + cx0;
    so11[it] = cy1 * 64 + cx1;
  }
  __syncthreads();

  // ===================== PHASE 2: main GEMM =====================
  const __hip_bfloat16* xb = xTh + ((size_t)b << 20);
  int vrow = tid >> 3;
  int chq  = tid & 7;
  int colz = (chq * 8) ^ ((vrow & 7) << 3);

  auto loadTaps = [&](int tkq, Taps& T) {
    int it = (tkq >> 2) * 32 + vrow;
    const __hip_bfloat16* base = xb + (tkq & 3) * 64 + chq * 8;
    T.t00 = *(const short8*)(base + (size_t)so00[it] * 256);
    T.t01 = *(const short8*)(base + (size_t)so01[it] * 256);
    T.t10 = *(const short8*)(base + (size_t)so10[it] * 256);
    T.t11 = *(const short8*)(base + (size_t)so11[it] * 256);
  };
  auto buildV = [&](int tkq, const Taps& T, int buf) {
    int it = (tkq >> 2) * 32 + vrow;
    float a00 = sw00[it], a01 = sw01[it], a10 = sw10[it], a11 = sw11[it];
    __hip_bfloat16 h8[8];
#pragma unroll
    for (int j = 0; j < 8; ++j) {
      float v = a00 * b2f(T.t00[j]) + a01 * b2f(T.t01[j])
              + a10 * b2f(T.t10[j]) + a11 * b2f(T.t11[j]);
      h8[j] = __float2bfloat16(v);
    }
    *(short8*)&sPV[buf][vrow * 64 + colz] = *(const short8*)h8;
  };
  auto loadW = [&](int tkq, short8 (&aw)[8]) {
#pragma unroll
    for (int fo = 0; fo < 4; ++fo)
#pragma unroll
      for (int kc = 0; kc < 2; ++kc)
        aw[fo * 2 + kc] = *(const short8*)((const char*)Wt3
                          + ((((size_t)tkq * 16 + (wv * 4 + fo)) * 2 + kc) << 10)
                          + lane * 16);
  };

  f32x4 zero4 = {0.f, 0.f, 0.f, 0.f};
  f32x4 acc[4][2];
#pragma unroll
  for (int fo = 0; fo < 4; ++fo)
#pragma unroll
    for (int fm = 0; fm < 2; ++fm) acc[fo][fm] = zero4;

  Taps TA, TB;
  short8 awA[8], awB[8];
  loadW(0, awA);
  loadTaps(0, TA);
  buildV(0, TA, 0);
  loadTaps(1, TB);
  asm volatile("s_waitcnt lgkmcnt(0)" ::: "memory");
  __builtin_amdgcn_s_barrier();

  auto body = [&](int tk, Taps& Tuse, Taps& Tload,
                  short8 (&awUse)[8], short8 (&awLoad)[8]) {
    int cb = tk & 1, nb = cb ^ 1;
    int tk1 = min(tk + 1, NKSTEP - 1), tk2 = min(tk + 2, NKSTEP - 1);
    loadW(tk1, awLoad);
    loadTaps(tk2, Tload);
    __builtin_amdgcn_sched_barrier(0);
    buildV(tk1, Tuse, nb);

    __builtin_amdgcn_s_setprio(1);
#pragma unroll
    for (int kc = 0; kc < 2; ++kc) {
      int cz = (kc * 32 + hi * 8) ^ ((lo & 7) << 3);
      short8 bv[2];
#pragma unroll
      for (int fm = 0; fm < 2; ++fm)
        bv[fm] = *(const short8*)&sPV[cb][(fm * 16 + lo) * 64 + cz];
#pragma unroll
      for (int fo = 0; fo < 4; ++fo)
#pragma unroll
        for (int fm = 0; fm < 2; ++fm)
          acc[fo][fm] = __builtin_amdgcn_mfma_f32_16x16x32_bf16(awUse[fo * 2 + kc], bv[fm], acc[fo][fm], 0, 0, 0);
    }
    __builtin_amdgcn_s_setprio(0);

    if (tk + 1 < NKSTEP) {
      asm volatile("s_waitcnt lgkmcnt(0)" ::: "memory");
      __builtin_amdgcn_s_barrier();
    }
  };

  for (int tkp = 0; tkp < NKSTEP; tkp += 2) {
    body(tkp,     TB, TA, awA, awB);
    body(tkp + 1, TA, TB, awB, awA);
  }

  // epilogue
  int hwbase = m0 & 4095;
#pragma unroll
  for (int fo = 0; fo < 4; ++fo) {
    int o = wv * 64 + fo * 16 + hi * 4;
#pragma unroll
    for (int fm = 0; fm < 2; ++fm) {
      int mloc = hwbase + fm * 16 + lo;
#pragma unroll
      for (int r = 0; r < 4; ++r)
        out[((size_t)(b * 256 + o + r)) * 4096 + mloc] = acc[fo][fm][r];
    }
  }
}

// ---------------------------------------------------------------------------
extern "C" void kernel_launch(void* const* d_in, const int* in_sizes, int n_in,
                              void* d_out, int out_size, void* d_ws, size_t ws_size,
                              hipStream_t stream) {
  (void)in_sizes; (void)n_in; (void)out_size; (void)ws_size;
  const float* x     = (const float*)d_in[0];
  const float* woff  = (const float*)d_in[1];
  const float* boff  = (const float*)d_in[2];
  const float* wconv = (const float*)d_in[3];
  char* ws = (char*)d_ws;
  __hip_bfloat16* xTh  = (__hip_bfloat16*)(ws + XT_OFF);
  __hip_bfloat16* Wt3  = (__hip_bfloat16*)(ws + WT_OFF);
  __hip_bfloat16* Wot3 = (__hip_bfloat16*)(ws + WOT_OFF);
  float* out = (float*)d_out;

  hipLaunchKernelGGL(k_prep,    dim3(3616), dim3(256), 0, stream, x, woff, wconv, Wt3, Wot3, xTh);
  hipLaunchKernelGGL(k23_fused, dim3(512),  dim3(256), 0, stream, xTh, Wt3, Wot3, boff, out);
}